// Round 7
// baseline (242.180 us; speedup 1.0000x reference)
//
#include <hip/hip_runtime.h>
#include <hip/hip_bf16.h>

// ---------------- types / helpers ----------------
typedef __attribute__((ext_vector_type(8))) short bf16x8;
typedef __attribute__((ext_vector_type(4))) float f32x4;

#define T_TOK 2048
#define HD 1024
#define ID 512
#define NE 16
#define TOPK 4
#define BK 32            // K-panel depth (bf16); 4 x 16B chunks per row
#define CPAD 16          // counts padded: one 64B line per expert counter

// pack two fp32 -> two bf16 (truncate): one v_perm_b32
__device__ __forceinline__ unsigned pk2(float a, float b) {
    return __builtin_amdgcn_perm(__float_as_uint(b), __float_as_uint(a),
                                 0x07060302u);
}
__device__ __forceinline__ short f2bf(float f) {  // RTNE
    unsigned u = __float_as_uint(f);
    return (short)((u + 0x7fffu + ((u >> 16) & 1u)) >> 16);
}
__device__ __forceinline__ float bf2f(short s) {
    return __uint_as_float(((unsigned)(unsigned short)s) << 16);
}
// async 16B-per-lane global->LDS DMA; lds dest = wave-uniform base + lane*16
__device__ __forceinline__ void load_lds16(const short* g, short* l) {
    __builtin_amdgcn_global_load_lds(
        (const __attribute__((address_space(1))) unsigned*)g,
        (__attribute__((address_space(3))) unsigned*)l, 16, 0, 0);
}

#define MFMA_BF16 __builtin_amdgcn_mfma_f32_16x16x32_bf16
#define FENCE() asm volatile("" ::: "memory")

// ---------------- kernel 1: router (+ x -> bf16, + expert assignment) -----
// Assignment fused: lanes 0..3 each issue ONE atomicAdd to line-padded
// counters in parallel (proven r6).
__global__ __launch_bounds__(256) void router_k(
        const float* __restrict__ x, const float* __restrict__ gw,
        const float* __restrict__ eb,
        int* __restrict__ tk_idx, float* __restrict__ tk_w,
        short* __restrict__ xb,
        int* __restrict__ counts, int* __restrict__ tok_list,
        int* __restrict__ pair_slot) {
    int wid  = (blockIdx.x * 256 + threadIdx.x) >> 6;   // token id
    int lane = threadIdx.x & 63;

    const float* xr = x + (size_t)wid * HD + lane * 16;
    float xv[16];
#pragma unroll
    for (int c = 0; c < 4; c++) {
        float4 v = *(const float4*)(xr + c * 4);
        xv[4 * c] = v.x; xv[4 * c + 1] = v.y; xv[4 * c + 2] = v.z; xv[4 * c + 3] = v.w;
    }
    {   // bf16 copy of x, coalesced
        union { uint4 q; unsigned u[4]; } w0, w1;
        w0.u[0] = pk2(xv[0], xv[1]);  w0.u[1] = pk2(xv[2], xv[3]);
        w0.u[2] = pk2(xv[4], xv[5]);  w0.u[3] = pk2(xv[6], xv[7]);
        w1.u[0] = pk2(xv[8], xv[9]);  w1.u[1] = pk2(xv[10], xv[11]);
        w1.u[2] = pk2(xv[12], xv[13]); w1.u[3] = pk2(xv[14], xv[15]);
        short* d = xb + ((size_t)wid << 10) + lane * 16;
        *(uint4*)d = w0.q;
        *(uint4*)(d + 8) = w1.q;
    }

    float logits[NE];
#pragma unroll
    for (int e = 0; e < NE; e++) {
        const float* gr = gw + e * HD + lane * 16;
        float p = 0.f;
#pragma unroll
        for (int c = 0; c < 4; c++) {
            float4 v = *(const float4*)(gr + c * 4);
            p += xv[4 * c] * v.x + xv[4 * c + 1] * v.y +
                 xv[4 * c + 2] * v.z + xv[4 * c + 3] * v.w;
        }
#pragma unroll
        for (int s = 32; s > 0; s >>= 1) p += __shfl_xor(p, s, 64);
        logits[e] = p;
    }

    float scores[NE], sc[NE];
#pragma unroll
    for (int e = 0; e < NE; e++) {
        scores[e] = 1.f / (1.f + __expf(-logits[e]));
        sc[e] = scores[e] + eb[e];
    }

    float gs[4];
#pragma unroll
    for (int g = 0; g < 4; g++) {
        float a = sc[4 * g], b = sc[4 * g + 1], c = sc[4 * g + 2], d = sc[4 * g + 3];
        float h1 = fmaxf(a, b), l1 = fminf(a, b);
        float h2 = fmaxf(c, d), l2 = fminf(c, d);
        gs[g] = fmaxf(h1, h2) + fmaxf(fminf(h1, h2), fmaxf(l1, l2));
    }
    int g0 = 0; float b0 = gs[0];
#pragma unroll
    for (int g = 1; g < 4; g++) if (gs[g] > b0) { b0 = gs[g]; g0 = g; }
    int g1 = -1; float b1 = -1e30f;
#pragma unroll
    for (int g = 0; g < 4; g++) if (g != g0 && gs[g] > b1) { b1 = gs[g]; g1 = g; }

    int taken = 0;
    int bid[TOPK]; float bsc[TOPK]; float wsum = 0.f;
#pragma unroll
    for (int k = 0; k < TOPK; k++) {
        float bv = -1e30f; int bi = 0; float bs = 0.f;
#pragma unroll
        for (int e = 0; e < NE; e++) {
            int grp = e >> 2;
            bool ok = ((grp == g0) || (grp == g1)) && !((taken >> e) & 1);
            if (ok && sc[e] > bv) { bv = sc[e]; bi = e; bs = scores[e]; }
        }
        taken |= (1 << bi);
        bid[k] = bi; bsc[k] = bs; wsum += bs;
    }
    // fused assignment: 4 parallel lanes, line-padded counters
    if (lane < TOPK) {
        float inv = 1.0f / (wsum + 1e-20f);
        int ee = bid[lane];
        int slot = atomicAdd(&counts[ee * CPAD], 1);
        tok_list[ee * T_TOK + slot] = wid;
        pair_slot[wid * TOPK + lane] = slot;
        tk_idx[wid * TOPK + lane] = ee;
        tk_w[wid * TOPK + lane]   = bsc[lane] * inv;
    }
}

// ---------------- kernel 2: GEMM1 (x @ [gate|up]^T, silu*up -> act) -------
// grid (experts=16, n_slices=8, m_tiles=16): linear%8 = e%8 (expert-affine
// XCD mapping, r5-proven). Block tile M=128 x N=64 (gate AND up), BK=32.
// A (x, bf16): DMA depth-2, 3 LDS bufs. B (gate/up, FP32 SOURCE): reg-
// staged — global fp32 loads double-buffered in regs (issued 1 panel
// ahead), pk2-truncated to bf16 (== old conv_k numerics), ds_write_b128
// into a single LDS buf. Swizzle on the LDS WRITE addr (linear global
// src); reads unchanged: slot qd^((r>>1)&3). vmcnt: per-iter issue order
// fixed [B(p+1) x4, xDMA(p+2) x2] -> steady wait vmcnt(8), tail 6 -> 0.
__global__ __launch_bounds__(256) void gemm1_k(
        const short* __restrict__ xb,
        const float* __restrict__ gpf,
        const float* __restrict__ upf,
        const int* __restrict__ counts,
        const int* __restrict__ tok_list,
        short* __restrict__ act) {
    __shared__ short xs[3][128 * BK];   // 8 KB per buf (DMA)
    __shared__ short gsm[64 * BK];      // 4 KB single buf (ds_write)
    __shared__ short usm[64 * BK];      // 4 KB single buf
    __shared__ int   tok_s[128];

    int e = blockIdx.x;
    int cnt = counts[e * CPAD];
    int base = blockIdx.z * 128;
    if (base >= cnt) return;
    int off = 0;
#pragma unroll
    for (int q = 0; q < NE; q++) if (q < e) off += counts[q * CPAD];
    int arow0 = off + base;

    int tid = threadIdx.x;
    if (tid < 128) {
        int s = base + tid;
        tok_s[tid] = (s < cnt) ? tok_list[e * T_TOK + s] : tok_list[e * T_TOK];
    }
    __syncthreads();

    int wv = tid >> 6, lane = tid & 63;
    int qd = lane >> 4, l16 = lane & 15;
    int wm = (wv >> 1) * 64, wn = (wv & 1) * 32;
    int nb0 = blockIdx.y * 64;

    // A staging (DMA, source-swizzled, linear LDS dest) — r6-proven
    const short* xsg[2]; short* xld[2];
#pragma unroll
    for (int i = 0; i < 2; i++) {
        int idx = i * 256 + tid, r = idx >> 2, c = idx & 3;
        int f = (r >> 1) & 3;
        xsg[i] = xb + ((size_t)tok_s[r] << 10) + ((c ^ f) << 3);
        xld[i] = &xs[0][(i * 256 + wv * 64) * 8];
    }
    // B staging (fp32 -> regs -> bf16 ds_write, swizzle on LDS write addr)
    int br = tid >> 2, bc = tid & 3;
    int bf_ = (br >> 1) & 3;
    const float* gsrc = gpf + (size_t)e * ID * HD + (size_t)(nb0 + br) * HD + bc * 8;
    const float* usrc = upf + (size_t)e * ID * HD + (size_t)(nb0 + br) * HD + bc * 8;
    short* gdst = &gsm[br * BK + ((bc ^ bf_) << 3)];
    short* udst = &usm[br * BK + ((bc ^ bf_) << 3)];

    f32x4 accg[4][2] = {};
    f32x4 accu[4][2] = {};
    float4 gA0, gA1, uA0, uA1, gB0, gB1, uB0, uB1;   // named sets (rule #20)

    auto XDMA = [&](int kp, int b) {
        load_lds16(xsg[0] + kp, xld[0] + b * (128 * BK));
        load_lds16(xsg[1] + kp, xld[1] + b * (128 * BK));
    };
    auto BLOAD = [&](int kp, float4& g0, float4& g1, float4& u0, float4& u1) {
        g0 = *(const float4*)(gsrc + kp);
        g1 = *(const float4*)(gsrc + kp + 4);
        u0 = *(const float4*)(usrc + kp);
        u1 = *(const float4*)(usrc + kp + 4);
    };
    auto BWRITE = [&](const float4& g0, const float4& g1,
                      const float4& u0, const float4& u1) {
        uint4 t;
        t.x = pk2(g0.x, g0.y); t.y = pk2(g0.z, g0.w);
        t.z = pk2(g1.x, g1.y); t.w = pk2(g1.z, g1.w);
        *(uint4*)gdst = t;
        t.x = pk2(u0.x, u0.y); t.y = pk2(u0.z, u0.w);
        t.z = pk2(u1.x, u1.y); t.w = pk2(u1.z, u1.w);
        *(uint4*)udst = t;
    };
    auto COMPUTE = [&](int b) {
        const short* xsb = xs[b];
        bf16x8 af[4], bg[2], bu[2];
#pragma unroll
        for (int i = 0; i < 4; i++) {
            int r = wm + i * 16 + l16;
            af[i] = *(const bf16x8*)&xsb[r * BK + ((qd ^ ((r >> 1) & 3)) << 3)];
        }
#pragma unroll
        for (int j = 0; j < 2; j++) {
            int r = wn + j * 16 + l16;
            int lo = r * BK + ((qd ^ ((r >> 1) & 3)) << 3);
            bg[j] = *(const bf16x8*)&gsm[lo];
            bu[j] = *(const bf16x8*)&usm[lo];
        }
#pragma unroll
        for (int i = 0; i < 4; i++)
#pragma unroll
            for (int j = 0; j < 2; j++) {
                accg[i][j] = MFMA_BF16(af[i], bg[j], accg[i][j], 0, 0, 0);
                accu[i][j] = MFMA_BF16(af[i], bu[j], accu[i][j], 0, 0, 0);
            }
    };

    constexpr int NP = HD / BK;   // 32 panels (even, >=4)
    // prologue: B(0)->setA, x(0)->buf0, x(1)->buf1
    BLOAD(0, gA0, gA1, uA0, uA1);
    FENCE();
    XDMA(0, 0); XDMA(BK, 1);
    FENCE();
#pragma unroll 1
    for (int p = 0; p < NP - 2; p += 2) {
        // even half: compute p (set A); prefetch B(p+1)->setB, x(p+2)
        BLOAD((p + 1) * BK, gB0, gB1, uB0, uB1);
        FENCE();
        XDMA((p + 2) * BK, (p + 2) % 3);
        FENCE();
        asm volatile("s_waitcnt vmcnt(8)" ::: "memory");  // x(p),B(p) landed
        BWRITE(gA0, gA1, uA0, uA1);
        asm volatile("s_waitcnt lgkmcnt(0)" ::: "memory");
        __builtin_amdgcn_s_barrier();
        FENCE();
        COMPUTE(p % 3);
        FENCE();
        __builtin_amdgcn_s_barrier();
        // odd half: compute p+1 (set B); prefetch B(p+2)->setA, x(p+3)
        BLOAD((p + 2) * BK, gA0, gA1, uA0, uA1);
        FENCE();
        XDMA((p + 3) * BK, (p + 3) % 3);
        FENCE();
        asm volatile("s_waitcnt vmcnt(8)" ::: "memory");
        BWRITE(gB0, gB1, uB0, uB1);
        asm volatile("s_waitcnt lgkmcnt(0)" ::: "memory");
        __builtin_amdgcn_s_barrier();
        FENCE();
        COMPUTE((p + 1) % 3);
        FENCE();
        __builtin_amdgcn_s_barrier();
    }
    // tail p = NP-2 (set A): B(NP-1)->setB, no more x
    BLOAD((NP - 1) * BK, gB0, gB1, uB0, uB1);
    FENCE();
    asm volatile("s_waitcnt vmcnt(6)" ::: "memory");
    BWRITE(gA0, gA1, uA0, uA1);
    asm volatile("s_waitcnt lgkmcnt(0)" ::: "memory");
    __builtin_amdgcn_s_barrier();
    FENCE();
    COMPUTE((NP - 2) % 3);
    FENCE();
    __builtin_amdgcn_s_barrier();
    // tail p = NP-1 (set B)
    asm volatile("s_waitcnt vmcnt(0)" ::: "memory");
    BWRITE(gB0, gB1, uB0, uB1);
    asm volatile("s_waitcnt lgkmcnt(0)" ::: "memory");
    __builtin_amdgcn_s_barrier();
    FENCE();
    COMPUTE((NP - 1) % 3);

    // epilogue: silu(g)*u -> bf16 act rows
#pragma unroll
    for (int i = 0; i < 4; i++)
#pragma unroll
        for (int j = 0; j < 2; j++)
#pragma unroll
            for (int r = 0; r < 4; r++) {
                int m = wm + i * 16 + qd * 4 + r;
                if (base + m < cnt) {
                    float g = accg[i][j][r], u = accu[i][j][r];
                    float a = g / (1.f + __expf(-g)) * u;
                    act[(size_t)(arow0 + m) * ID + nb0 + wn + j * 16 + l16] = f2bf(a);
                }
            }
}

// ---------------- kernel 3: GEMM2 (act @ down^T -> yexp bf16) -------------
// grid (experts=16, h_slices=8, m_tiles=16), expert-affine. Block tile
// M=128 x N=128, BK=32. A (act, bf16): DMA depth-2, 3 bufs. B (down,
// FP32 SOURCE): reg-staged like gemm1. NP=16.
__global__ __launch_bounds__(256) void gemm2_k(
        const short* __restrict__ act,
        const float* __restrict__ dpf,
        const int* __restrict__ counts,
        short* __restrict__ yexp) {
    __shared__ short as_[3][128 * BK];  // 8 KB per buf (DMA)
    __shared__ short dsm[128 * BK];     // 8 KB single buf (ds_write)

    int e = blockIdx.x;
    int cnt = counts[e * CPAD];
    int base = blockIdx.z * 128;
    if (base >= cnt) return;
    int off = 0;
#pragma unroll
    for (int q = 0; q < NE; q++) if (q < e) off += counts[q * CPAD];
    int arow0 = off + base;

    int tid = threadIdx.x;
    int wv = tid >> 6, lane = tid & 63;
    int qd = lane >> 4, l16 = lane & 15;
    int wm = (wv >> 1) * 64, wn = (wv & 1) * 64;
    int hb0 = blockIdx.y * 128;

    // A staging (DMA, source-swizzled)
    const short* asg[2]; short* ald[2];
#pragma unroll
    for (int i = 0; i < 2; i++) {
        int idx = i * 256 + tid, r = idx >> 2, c = idx & 3;
        int f = (r >> 1) & 3;
        asg[i] = act + (size_t)(arow0 + r) * ID + ((c ^ f) << 3);
        ald[i] = &as_[0][(i * 256 + wv * 64) * 8];
    }
    // B staging: 128 rows x 4 chunks = 512 over 256 threads -> 2/thread
    const float* dsrc0; const float* dsrc1; short* ddst0; short* ddst1;
    {
        int idx = tid, r = idx >> 2, c = idx & 3;
        int f = (r >> 1) & 3;
        dsrc0 = dpf + (size_t)e * HD * ID + (size_t)(hb0 + r) * ID + c * 8;
        ddst0 = &dsm[r * BK + ((c ^ f) << 3)];
        idx = 256 + tid; r = idx >> 2; c = idx & 3;
        f = (r >> 1) & 3;
        dsrc1 = dpf + (size_t)e * HD * ID + (size_t)(hb0 + r) * ID + c * 8;
        ddst1 = &dsm[r * BK + ((c ^ f) << 3)];
    }

    f32x4 acc[4][4] = {};
    float4 dA0, dA1, dA2, dA3, dB0, dB1, dB2, dB3;   // named sets

    auto XDMA = [&](int kp, int b) {
        load_lds16(asg[0] + kp, ald[0] + b * (128 * BK));
        load_lds16(asg[1] + kp, ald[1] + b * (128 * BK));
    };
    auto BLOAD = [&](int kp, float4& d0, float4& d1, float4& d2, float4& d3) {
        d0 = *(const float4*)(dsrc0 + kp);
        d1 = *(const float4*)(dsrc0 + kp + 4);
        d2 = *(const float4*)(dsrc1 + kp);
        d3 = *(const float4*)(dsrc1 + kp + 4);
    };
    auto BWRITE = [&](const float4& d0, const float4& d1,
                      const float4& d2, const float4& d3) {
        uint4 t;
        t.x = pk2(d0.x, d0.y); t.y = pk2(d0.z, d0.w);
        t.z = pk2(d1.x, d1.y); t.w = pk2(d1.z, d1.w);
        *(uint4*)ddst0 = t;
        t.x = pk2(d2.x, d2.y); t.y = pk2(d2.z, d2.w);
        t.z = pk2(d3.x, d3.y); t.w = pk2(d3.z, d3.w);
        *(uint4*)ddst1 = t;
    };
    auto COMPUTE = [&](int b) {
        const short* asb = as_[b];
        bf16x8 af[4], bd[4];
#pragma unroll
        for (int i = 0; i < 4; i++) {
            int r = wm + i * 16 + l16;
            af[i] = *(const bf16x8*)&asb[r * BK + ((qd ^ ((r >> 1) & 3)) << 3)];
            int r2 = wn + i * 16 + l16;
            bd[i] = *(const bf16x8*)&dsm[r2 * BK + ((qd ^ ((r2 >> 1) & 3)) << 3)];
        }
#pragma unroll
        for (int i = 0; i < 4; i++)
#pragma unroll
            for (int j = 0; j < 4; j++)
                acc[i][j] = MFMA_BF16(af[i], bd[j], acc[i][j], 0, 0, 0);
    };

    constexpr int NP = ID / BK;   // 16 panels (even, >=4)
    BLOAD(0, dA0, dA1, dA2, dA3);
    FENCE();
    XDMA(0, 0); XDMA(BK, 1);
    FENCE();
#pragma unroll 1
    for (int p = 0; p < NP - 2; p += 2) {
        BLOAD((p + 1) * BK, dB0, dB1, dB2, dB3);
        FENCE();
        XDMA((p + 2) * BK, (p + 2) % 3);
        FENCE();
        asm volatile("s_waitcnt vmcnt(8)" ::: "memory");
        BWRITE(dA0, dA1, dA2, dA3);
        asm volatile("s_waitcnt lgkmcnt(0)" ::: "memory");
        __builtin_amdgcn_s_barrier();
        FENCE();
        COMPUTE(p % 3);
        FENCE();
        __builtin_amdgcn_s_barrier();
        BLOAD((p + 2) * BK, dA0, dA1, dA2, dA3);
        FENCE();
        XDMA((p + 3) * BK, (p + 3) % 3);
        FENCE();
        asm volatile("s_waitcnt vmcnt(8)" ::: "memory");
        BWRITE(dB0, dB1, dB2, dB3);
        asm volatile("s_waitcnt lgkmcnt(0)" ::: "memory");
        __builtin_amdgcn_s_barrier();
        FENCE();
        COMPUTE((p + 1) % 3);
        FENCE();
        __builtin_amdgcn_s_barrier();
    }
    BLOAD((NP - 1) * BK, dB0, dB1, dB2, dB3);
    FENCE();
    asm volatile("s_waitcnt vmcnt(6)" ::: "memory");
    BWRITE(dA0, dA1, dA2, dA3);
    asm volatile("s_waitcnt lgkmcnt(0)" ::: "memory");
    __builtin_amdgcn_s_barrier();
    FENCE();
    COMPUTE((NP - 2) % 3);
    FENCE();
    __builtin_amdgcn_s_barrier();
    asm volatile("s_waitcnt vmcnt(0)" ::: "memory");
    BWRITE(dB0, dB1, dB2, dB3);
    asm volatile("s_waitcnt lgkmcnt(0)" ::: "memory");
    __builtin_amdgcn_s_barrier();
    FENCE();
    COMPUTE((NP - 1) % 3);

#pragma unroll
    for (int i = 0; i < 4; i++)
#pragma unroll
        for (int j = 0; j < 4; j++)
#pragma unroll
            for (int r = 0; r < 4; r++) {
                int m = wm + i * 16 + qd * 4 + r;
                if (base + m < cnt)
                    yexp[(size_t)(arow0 + m) * HD + hb0 + wn + j * 16 + l16] =
                        f2bf(acc[i][j][r]);
            }
}

// ---------------- kernel 4: weighted combine (atomic-free) ----------------
__global__ __launch_bounds__(256) void combine_k(
        const short* __restrict__ yexp,
        const int* __restrict__ counts,
        const int* __restrict__ tk_idx, const float* __restrict__ tk_w,
        const int* __restrict__ pair_slot,
        float* __restrict__ out) {
    __shared__ int offs_s[NE];
    if (threadIdx.x == 0) {
        int a = 0;
#pragma unroll
        for (int e = 0; e < NE; e++) { offs_s[e] = a; a += counts[e * CPAD]; }
    }
    __syncthreads();

    int t = blockIdx.x * 2 + (threadIdx.x >> 7);
    int i = threadIdx.x & 127;          // col group of 8
    float acc[8] = {};
#pragma unroll
    for (int k = 0; k < TOPK; k++) {
        int p = t * TOPK + k;
        int e = tk_idx[p];
        int row = offs_s[e] + pair_slot[p];
        float w = tk_w[p];
        bf16x8 v = *(const bf16x8*)(yexp + (size_t)row * HD + i * 8);
#pragma unroll
        for (int j = 0; j < 8; j++) acc[j] += w * bf2f(v[j]);
    }
    float4 o0 = {acc[0], acc[1], acc[2], acc[3]};
    float4 o1 = {acc[4], acc[5], acc[6], acc[7]};
    float* d = out + (size_t)t * HD + i * 8;
    *(float4*)d = o0;
    *(float4*)(d + 4) = o1;
}

// ---------------- launch ----------------
extern "C" void kernel_launch(void* const* d_in, const int* in_sizes, int n_in,
                              void* d_out, int out_size, void* d_ws, size_t ws_size,
                              hipStream_t stream) {
    const float* x  = (const float*)d_in[0];   // hidden_states [T,H]
    const float* gw = (const float*)d_in[1];   // gate_weight  [E,H]
    const float* eb = (const float*)d_in[2];   // e_bias       [E]
    const float* gp = (const float*)d_in[3];   // gate_proj [E,I,H] fp32
    const float* up = (const float*)d_in[4];   // up_proj   [E,I,H] fp32
    const float* dp = (const float*)d_in[5];   // down_proj [E,H,I] fp32

    // workspace: no bf16 weight copies anymore (gemms consume fp32 direct)
    short* xb   = (short*)d_ws;                        // 2048x1024 bf16
    short* act  = xb + (size_t)T_TOK * HD;             // (8192+128)x512 bf16
    short* yexp = act + (size_t)(T_TOK * TOPK + 128) * ID;  // 8192x1024 bf16
    int* counts    = (int*)(yexp + (size_t)T_TOK * TOPK * HD); // NE*CPAD
    int* tok_list  = counts + NE * CPAD;              // E*T
    int* pair_slot = tok_list + NE * T_TOK;           // T*4
    int* tk_idx    = pair_slot + T_TOK * TOPK;        // T*4
    float* tk_w    = (float*)(tk_idx + T_TOK * TOPK); // T*4

    hipMemsetAsync(counts, 0, NE * CPAD * sizeof(int), stream);

    router_k<<<T_TOK / 4, 256, 0, stream>>>(x, gw, eb, tk_idx, tk_w, xb,
                                            counts, tok_list, pair_slot);
    gemm1_k<<<dim3(NE, ID / 64, T_TOK / 128), 256, 0, stream>>>(
        xb, gp, up, counts, tok_list, act);
    gemm2_k<<<dim3(NE, HD / 128, T_TOK / 128), 256, 0, stream>>>(
        act, dp, counts, yexp);
    combine_k<<<T_TOK / 2, 256, 0, stream>>>(yexp, counts, tk_idx, tk_w,
                                             pair_slot, (float*)d_out);
}

// Round 8
// 241.238 us; speedup vs baseline: 1.0039x; 1.0039x over previous
//
#include <hip/hip_runtime.h>
#include <hip/hip_bf16.h>

// ---------------- types / helpers ----------------
typedef __attribute__((ext_vector_type(8))) short bf16x8;
typedef __attribute__((ext_vector_type(4))) float f32x4;

#define T_TOK 2048
#define HD 1024
#define ID 512
#define NE 16
#define TOPK 4
#define BK 32            // K-panel depth (bf16); 4 x 16B chunks per row
#define WELEM (HD*ID*NE) // elems per weight tensor = 8388608
#define CPAD 16          // counts padded: one 64B line per expert counter

// pack two fp32 -> two bf16 (truncate): one v_perm_b32
__device__ __forceinline__ unsigned pk2(float a, float b) {
    return __builtin_amdgcn_perm(__float_as_uint(b), __float_as_uint(a),
                                 0x07060302u);
}
__device__ __forceinline__ bf16x8 cvt8(const float* __restrict__ p) {
    float4 a = *(const float4*)p;
    float4 b = *(const float4*)(p + 4);
    union { bf16x8 v; unsigned u[4]; } r;
    r.u[0] = pk2(a.x, a.y); r.u[1] = pk2(a.z, a.w);
    r.u[2] = pk2(b.x, b.y); r.u[3] = pk2(b.z, b.w);
    return r.v;
}
__device__ __forceinline__ short f2bf(float f) {  // RTNE
    unsigned u = __float_as_uint(f);
    return (short)((u + 0x7fffu + ((u >> 16) & 1u)) >> 16);
}
__device__ __forceinline__ float bf2f(short s) {
    return __uint_as_float(((unsigned)(unsigned short)s) << 16);
}
// async 16B-per-lane global->LDS DMA; lds dest = wave-uniform base + lane*16
__device__ __forceinline__ void load_lds16(const short* g, short* l) {
    __builtin_amdgcn_global_load_lds(
        (const __attribute__((address_space(1))) unsigned*)g,
        (__attribute__((address_space(3))) unsigned*)l, 16, 0, 0);
}

#define MFMA_BF16 __builtin_amdgcn_mfma_f32_16x16x32_bf16

// ---------------- kernel 0: fp32 -> bf16 convert (3 tensors) --------------
// Also zeroes the padded counts[] (runs before router in stream order).
__global__ __launch_bounds__(256) void conv_k(
        const float* __restrict__ s0, short* __restrict__ d0,
        const float* __restrict__ s1, short* __restrict__ d1,
        const float* __restrict__ s2, short* __restrict__ d2,
        int* __restrict__ counts) {
    if (blockIdx.x == 0 && blockIdx.y == 0)
        counts[threadIdx.x] = 0;            // 256 = NE*CPAD exactly
    const float* src = (blockIdx.y == 0) ? s0 : (blockIdx.y == 1) ? s1 : s2;
    short* dst       = (blockIdx.y == 0) ? d0 : (blockIdx.y == 1) ? d1 : d2;
    size_t i = ((size_t)blockIdx.x * 256 + threadIdx.x) * 8;
    union { bf16x8 v; uint4 q; } r;
    r.v = cvt8(src + i);
    *(uint4*)(dst + i) = r.q;
}

// ---------------- kernel 1: router (+ x -> bf16, + expert assignment) -----
// Assignment fused: lanes 0..3 each issue ONE atomicAdd to line-padded
// counters in parallel (proven r6).
__global__ __launch_bounds__(256) void router_k(
        const float* __restrict__ x, const float* __restrict__ gw,
        const float* __restrict__ eb,
        int* __restrict__ tk_idx, float* __restrict__ tk_w,
        short* __restrict__ xb,
        int* __restrict__ counts, int* __restrict__ tok_list,
        int* __restrict__ pair_slot) {
    int wid  = (blockIdx.x * 256 + threadIdx.x) >> 6;   // token id
    int lane = threadIdx.x & 63;

    const float* xr = x + (size_t)wid * HD + lane * 16;
    float xv[16];
#pragma unroll
    for (int c = 0; c < 4; c++) {
        float4 v = *(const float4*)(xr + c * 4);
        xv[4 * c] = v.x; xv[4 * c + 1] = v.y; xv[4 * c + 2] = v.z; xv[4 * c + 3] = v.w;
    }
    {   // bf16 copy of x, coalesced
        union { uint4 q; unsigned u[4]; } w0, w1;
        w0.u[0] = pk2(xv[0], xv[1]);  w0.u[1] = pk2(xv[2], xv[3]);
        w0.u[2] = pk2(xv[4], xv[5]);  w0.u[3] = pk2(xv[6], xv[7]);
        w1.u[0] = pk2(xv[8], xv[9]);  w1.u[1] = pk2(xv[10], xv[11]);
        w1.u[2] = pk2(xv[12], xv[13]); w1.u[3] = pk2(xv[14], xv[15]);
        short* d = xb + ((size_t)wid << 10) + lane * 16;
        *(uint4*)d = w0.q;
        *(uint4*)(d + 8) = w1.q;
    }

    float logits[NE];
#pragma unroll
    for (int e = 0; e < NE; e++) {
        const float* gr = gw + e * HD + lane * 16;
        float p = 0.f;
#pragma unroll
        for (int c = 0; c < 4; c++) {
            float4 v = *(const float4*)(gr + c * 4);
            p += xv[4 * c] * v.x + xv[4 * c + 1] * v.y +
                 xv[4 * c + 2] * v.z + xv[4 * c + 3] * v.w;
        }
#pragma unroll
        for (int s = 32; s > 0; s >>= 1) p += __shfl_xor(p, s, 64);
        logits[e] = p;
    }

    float scores[NE], sc[NE];
#pragma unroll
    for (int e = 0; e < NE; e++) {
        scores[e] = 1.f / (1.f + __expf(-logits[e]));
        sc[e] = scores[e] + eb[e];
    }

    float gs[4];
#pragma unroll
    for (int g = 0; g < 4; g++) {
        float a = sc[4 * g], b = sc[4 * g + 1], c = sc[4 * g + 2], d = sc[4 * g + 3];
        float h1 = fmaxf(a, b), l1 = fminf(a, b);
        float h2 = fmaxf(c, d), l2 = fminf(c, d);
        gs[g] = fmaxf(h1, h2) + fmaxf(fminf(h1, h2), fmaxf(l1, l2));
    }
    int g0 = 0; float b0 = gs[0];
#pragma unroll
    for (int g = 1; g < 4; g++) if (gs[g] > b0) { b0 = gs[g]; g0 = g; }
    int g1 = -1; float b1 = -1e30f;
#pragma unroll
    for (int g = 0; g < 4; g++) if (g != g0 && gs[g] > b1) { b1 = gs[g]; g1 = g; }

    int taken = 0;
    int bid[TOPK]; float bsc[TOPK]; float wsum = 0.f;
#pragma unroll
    for (int k = 0; k < TOPK; k++) {
        float bv = -1e30f; int bi = 0; float bs = 0.f;
#pragma unroll
        for (int e = 0; e < NE; e++) {
            int grp = e >> 2;
            bool ok = ((grp == g0) || (grp == g1)) && !((taken >> e) & 1);
            if (ok && sc[e] > bv) { bv = sc[e]; bi = e; bs = scores[e]; }
        }
        taken |= (1 << bi);
        bid[k] = bi; bsc[k] = bs; wsum += bs;
    }
    // fused assignment: 4 parallel lanes, line-padded counters
    if (lane < TOPK) {
        float inv = 1.0f / (wsum + 1e-20f);
        int ee = bid[lane];
        int slot = atomicAdd(&counts[ee * CPAD], 1);
        tok_list[ee * T_TOK + slot] = wid;
        pair_slot[wid * TOPK + lane] = slot;
        tk_idx[wid * TOPK + lane] = ee;
        tk_w[wid * TOPK + lane]   = bsc[lane] * inv;
    }
}

// ---------------- kernel 2: GEMM1 (x @ [gate|up]^T, silu*up -> act) -------
// grid (experts=16, n_slices=8, m_tiles=16): linear%8 = e%8 (expert-affine
// XCD mapping, r5-proven). Block tile M=128 x N=64 (gate AND up), BK=32,
// 4 waves (2x2), wave 64x32. DEPTH-3 pipeline: 4 LDS buffers (64.5 KB ->
// 2 blocks/CU; grid only supplies ~2/CU anyway, so latency hiding must
// come from pipeline depth, not TLP). Counted vmcnt(12) steady (3 panels
// x 4 loads in flight), tail 8 -> 4 -> 0. Chunk swizzle: source chunk
// c^((r>>1)&3), read slot qd^((r>>1)&3) (r5/r6-proven).
__global__ __launch_bounds__(256) void gemm1_k(
        const short* __restrict__ xb,
        const short* __restrict__ gpb,
        const short* __restrict__ upb,
        const int* __restrict__ counts,
        const int* __restrict__ tok_list,
        short* __restrict__ act) {
    __shared__ short xs[4][128 * BK];   // 8 KB per buf
    __shared__ short gs[4][64 * BK];    // 4 KB per buf
    __shared__ short us[4][64 * BK];    // 4 KB per buf
    __shared__ int   tok_s[128];

    int e = blockIdx.x;
    int cnt = counts[e * CPAD];
    int base = blockIdx.z * 128;
    if (base >= cnt) return;
    int off = 0;
#pragma unroll
    for (int q = 0; q < NE; q++) if (q < e) off += counts[q * CPAD];
    int arow0 = off + base;

    int tid = threadIdx.x;
    if (tid < 128) {
        int s = base + tid;
        tok_s[tid] = (s < cnt) ? tok_list[e * T_TOK + s] : tok_list[e * T_TOK];
    }
    __syncthreads();

    int wv = tid >> 6, lane = tid & 63;
    int qd = lane >> 4, l16 = lane & 15;
    int wm = (wv >> 1) * 64, wn = (wv & 1) * 32;
    int nb0 = blockIdx.y * 64;
    const short* gp = gpb + (size_t)e * ID * HD + (size_t)nb0 * HD;
    const short* up = upb + (size_t)e * ID * HD + (size_t)nb0 * HD;

    // staging: 16B chunks, 4 per row. x: 512 chunks -> 2/thread; g,u: 1 each.
    const short* xsg[2]; short* xld[2];
#pragma unroll
    for (int i = 0; i < 2; i++) {
        int idx = i * 256 + tid, r = idx >> 2, c = idx & 3;
        int f = (r >> 1) & 3;
        xsg[i] = xb + ((size_t)tok_s[r] << 10) + ((c ^ f) << 3);
        xld[i] = &xs[0][(i * 256 + wv * 64) * 8];
    }
    const short* gsg; const short* usg; short* gld; short* uld;
    {
        int r = tid >> 2, c = tid & 3;
        int f = (r >> 1) & 3;
        size_t so = (size_t)r * HD + ((c ^ f) << 3);
        gsg = gp + so;
        usg = up + so;
        gld = &gs[0][(wv * 64) * 8];
        uld = &us[0][(wv * 64) * 8];
    }

    f32x4 accg[4][2] = {};
    f32x4 accu[4][2] = {};

    // 4 global_load_lds per thread per panel
    auto STAGE = [&](int kp, int b) {
        load_lds16(xsg[0] + kp, xld[0] + b * (128 * BK));
        load_lds16(xsg[1] + kp, xld[1] + b * (128 * BK));
        load_lds16(gsg + kp, gld + b * (64 * BK));
        load_lds16(usg + kp, uld + b * (64 * BK));
    };
    auto COMPUTE = [&](int b) {
        const short* xsb = xs[b];
        const short* gsb = gs[b];
        const short* usb = us[b];
        bf16x8 af[4], bg[2], bu[2];
#pragma unroll
        for (int i = 0; i < 4; i++) {
            int r = wm + i * 16 + l16;
            af[i] = *(const bf16x8*)&xsb[r * BK + ((qd ^ ((r >> 1) & 3)) << 3)];
        }
#pragma unroll
        for (int j = 0; j < 2; j++) {
            int r = wn + j * 16 + l16;
            int lo = r * BK + ((qd ^ ((r >> 1) & 3)) << 3);
            bg[j] = *(const bf16x8*)&gsb[lo];
            bu[j] = *(const bf16x8*)&usb[lo];
        }
#pragma unroll
        for (int i = 0; i < 4; i++)
#pragma unroll
            for (int j = 0; j < 2; j++) {
                accg[i][j] = MFMA_BF16(af[i], bg[j], accg[i][j], 0, 0, 0);
                accu[i][j] = MFMA_BF16(af[i], bu[j], accu[i][j], 0, 0, 0);
            }
    };

    constexpr int NP = HD / BK;   // 32 panels (mult of 4)
    STAGE(0, 0); STAGE(BK, 1); STAGE(2 * BK, 2);
    int b = 0;
#pragma unroll 1
    for (int p = 0; p < NP; ++p) {
        int bn = b + 3; if (bn >= 4) bn -= 4;
        if (p + 3 < NP) {
            STAGE((p + 3) * BK, bn);
            asm volatile("s_waitcnt vmcnt(12)" ::: "memory"); // panel p landed
        } else if (p + 2 < NP) {
            asm volatile("s_waitcnt vmcnt(8)" ::: "memory");
        } else if (p + 1 < NP) {
            asm volatile("s_waitcnt vmcnt(4)" ::: "memory");
        } else {
            asm volatile("s_waitcnt vmcnt(0)" ::: "memory");
        }
        __builtin_amdgcn_s_barrier();
        asm volatile("" ::: "memory");   // no ds_read hoists above barrier
        COMPUTE(b);
        asm volatile("" ::: "memory");   // no ds_read sinks below barrier
        __builtin_amdgcn_s_barrier();    // buf b free for DMA overwrite
        b = (b == 3) ? 0 : b + 1;
    }

    // epilogue: silu(g)*u -> bf16 act rows
#pragma unroll
    for (int i = 0; i < 4; i++)
#pragma unroll
        for (int j = 0; j < 2; j++)
#pragma unroll
            for (int r = 0; r < 4; r++) {
                int m = wm + i * 16 + qd * 4 + r;
                if (base + m < cnt) {
                    float g = accg[i][j][r], u = accu[i][j][r];
                    float a = g / (1.f + __expf(-g)) * u;
                    act[(size_t)(arow0 + m) * ID + nb0 + wn + j * 16 + l16] = f2bf(a);
                }
            }
}

// ---------------- kernel 3: GEMM2 (act @ down^T -> yexp bf16) -------------
// grid (experts=16, h_slices=8, m_tiles=16): expert-affine like gemm1.
// Block tile M=128 x N=128, BK=32, wave 64x64. DEPTH-3 pipeline: 4 LDS
// buffers (64 KB -> 2 blocks/CU, = grid supply), vmcnt(12) steady.
__global__ __launch_bounds__(256) void gemm2_k(
        const short* __restrict__ act,
        const short* __restrict__ dpb,
        const int* __restrict__ counts,
        short* __restrict__ yexp) {
    __shared__ short as_[4][128 * BK];  // 8 KB per buf
    __shared__ short ds_[4][128 * BK];  // 8 KB per buf

    int e = blockIdx.x;
    int cnt = counts[e * CPAD];
    int base = blockIdx.z * 128;
    if (base >= cnt) return;
    int off = 0;
#pragma unroll
    for (int q = 0; q < NE; q++) if (q < e) off += counts[q * CPAD];
    int arow0 = off + base;

    int tid = threadIdx.x;
    int wv = tid >> 6, lane = tid & 63;
    int qd = lane >> 4, l16 = lane & 15;
    int wm = (wv >> 1) * 64, wn = (wv & 1) * 64;
    int hb0 = blockIdx.y * 128;
    const short* dp = dpb + (size_t)e * HD * ID + (size_t)hb0 * ID;

    // staging: A 512 chunks -> 2/thread; B 512 chunks -> 2/thread.
    const short* asg[2]; const short* dsg[2]; short* ald[2]; short* dld[2];
#pragma unroll
    for (int i = 0; i < 2; i++) {
        int idx = i * 256 + tid, r = idx >> 2, c = idx & 3;
        int f = (r >> 1) & 3;
        int sw = (c ^ f) << 3;
        asg[i] = act + (size_t)(arow0 + r) * ID + sw;
        dsg[i] = dp + (size_t)r * ID + sw;
        ald[i] = &as_[0][(i * 256 + wv * 64) * 8];
        dld[i] = &ds_[0][(i * 256 + wv * 64) * 8];
    }

    f32x4 acc[4][4] = {};

    auto STAGE = [&](int kp, int b) {
        load_lds16(asg[0] + kp, ald[0] + b * (128 * BK));
        load_lds16(asg[1] + kp, ald[1] + b * (128 * BK));
        load_lds16(dsg[0] + kp, dld[0] + b * (128 * BK));
        load_lds16(dsg[1] + kp, dld[1] + b * (128 * BK));
    };
    auto COMPUTE = [&](int b) {
        const short* asb = as_[b];
        const short* dsb = ds_[b];
        bf16x8 af[4], bd[4];
#pragma unroll
        for (int i = 0; i < 4; i++) {
            int r = wm + i * 16 + l16;
            af[i] = *(const bf16x8*)&asb[r * BK + ((qd ^ ((r >> 1) & 3)) << 3)];
            int r2 = wn + i * 16 + l16;
            bd[i] = *(const bf16x8*)&dsb[r2 * BK + ((qd ^ ((r2 >> 1) & 3)) << 3)];
        }
#pragma unroll
        for (int i = 0; i < 4; i++)
#pragma unroll
            for (int j = 0; j < 4; j++)
                acc[i][j] = MFMA_BF16(af[i], bd[j], acc[i][j], 0, 0, 0);
    };

    constexpr int NP = ID / BK;   // 16 panels (mult of 4)
    STAGE(0, 0); STAGE(BK, 1); STAGE(2 * BK, 2);
    int b = 0;
#pragma unroll 1
    for (int p = 0; p < NP; ++p) {
        int bn = b + 3; if (bn >= 4) bn -= 4;
        if (p + 3 < NP) {
            STAGE((p + 3) * BK, bn);
            asm volatile("s_waitcnt vmcnt(12)" ::: "memory");
        } else if (p + 2 < NP) {
            asm volatile("s_waitcnt vmcnt(8)" ::: "memory");
        } else if (p + 1 < NP) {
            asm volatile("s_waitcnt vmcnt(4)" ::: "memory");
        } else {
            asm volatile("s_waitcnt vmcnt(0)" ::: "memory");
        }
        __builtin_amdgcn_s_barrier();
        asm volatile("" ::: "memory");
        COMPUTE(b);
        asm volatile("" ::: "memory");
        __builtin_amdgcn_s_barrier();
        b = (b == 3) ? 0 : b + 1;
    }

#pragma unroll
    for (int i = 0; i < 4; i++)
#pragma unroll
        for (int j = 0; j < 4; j++)
#pragma unroll
            for (int r = 0; r < 4; r++) {
                int m = wm + i * 16 + qd * 4 + r;
                if (base + m < cnt)
                    yexp[(size_t)(arow0 + m) * HD + hb0 + wn + j * 16 + l16] =
                        f2bf(acc[i][j][r]);
            }
}

// ---------------- kernel 4: weighted combine (atomic-free) ----------------
// 2 tokens per block; thread covers 8 cols. Computes expert offsets from
// padded counts locally. Fully overwrites out.
__global__ __launch_bounds__(256) void combine_k(
        const short* __restrict__ yexp,
        const int* __restrict__ counts,
        const int* __restrict__ tk_idx, const float* __restrict__ tk_w,
        const int* __restrict__ pair_slot,
        float* __restrict__ out) {
    __shared__ int offs_s[NE];
    if (threadIdx.x == 0) {
        int a = 0;
#pragma unroll
        for (int e = 0; e < NE; e++) { offs_s[e] = a; a += counts[e * CPAD]; }
    }
    __syncthreads();

    int t = blockIdx.x * 2 + (threadIdx.x >> 7);
    int i = threadIdx.x & 127;          // col group of 8
    float acc[8] = {};
#pragma unroll
    for (int k = 0; k < TOPK; k++) {
        int p = t * TOPK + k;
        int e = tk_idx[p];
        int row = offs_s[e] + pair_slot[p];
        float w = tk_w[p];
        bf16x8 v = *(const bf16x8*)(yexp + (size_t)row * HD + i * 8);
#pragma unroll
        for (int j = 0; j < 8; j++) acc[j] += w * bf2f(v[j]);
    }
    float4 o0 = {acc[0], acc[1], acc[2], acc[3]};
    float4 o1 = {acc[4], acc[5], acc[6], acc[7]};
    float* d = out + (size_t)t * HD + i * 8;
    *(float4*)d = o0;
    *(float4*)(d + 4) = o1;
}

// ---------------- launch ----------------
extern "C" void kernel_launch(void* const* d_in, const int* in_sizes, int n_in,
                              void* d_out, int out_size, void* d_ws, size_t ws_size,
                              hipStream_t stream) {
    const float* x  = (const float*)d_in[0];   // hidden_states [T,H]
    const float* gw = (const float*)d_in[1];   // gate_weight  [E,H]
    const float* eb = (const float*)d_in[2];   // e_bias       [E]
    const float* gp = (const float*)d_in[3];   // gate_proj [E,I,H]
    const float* up = (const float*)d_in[4];   // up_proj   [E,I,H]
    const float* dp = (const float*)d_in[5];   // down_proj [E,H,I]

    short* gpb = (short*)d_ws;                  // bf16 weights: 3 x 16.8 MB
    short* upb = gpb + WELEM;
    short* dpb = upb + WELEM;
    short* xb  = dpb + WELEM;                   // x bf16: 2048x1024
    short* act = xb + (size_t)T_TOK * HD;       // (8192+128) x 512 bf16
    int* counts    = (int*)(act + (size_t)(T_TOK * TOPK + 128) * ID); // NE*CPAD
    int* tok_list  = counts + NE * CPAD;              // E*T
    int* pair_slot = tok_list + NE * T_TOK;           // T*4
    int* tk_idx    = pair_slot + T_TOK * TOPK;        // T*4
    float* tk_w    = (float*)(tk_idx + T_TOK * TOPK); // T*4
    // yexp bf16 (8192 x 1024 = 16.8 MB) aliases gpb (dead after gemm1;
    // exact size match). Same-stream ordering makes this safe.
    short* yexp = gpb;

    conv_k<<<dim3(WELEM / 8 / 256, 3), 256, 0, stream>>>(gp, gpb, up, upb,
                                                         dp, dpb, counts);
    router_k<<<T_TOK / 4, 256, 0, stream>>>(x, gw, eb, tk_idx, tk_w, xb,
                                            counts, tok_list, pair_slot);
    gemm1_k<<<dim3(NE, ID / 64, T_TOK / 128), 256, 0, stream>>>(
        xb, gpb, upb, counts, tok_list, act);
    gemm2_k<<<dim3(NE, HD / 128, T_TOK / 128), 256, 0, stream>>>(
        act, dpb, counts, yexp);
    combine_k<<<T_TOK / 2, 256, 0, stream>>>(yexp, counts, tk_idx, tk_w,
                                             pair_slot, (float*)d_out);
}

// Round 9
// 206.251 us; speedup vs baseline: 1.1742x; 1.1696x over previous
//
#include <hip/hip_runtime.h>
#include <hip/hip_bf16.h>

// ---------------- types / helpers ----------------
typedef __attribute__((ext_vector_type(8))) short bf16x8;
typedef __attribute__((ext_vector_type(4))) float f32x4;

#define T_TOK 2048
#define HD 1024
#define ID 512
#define NE 16
#define TOPK 4
#define BK 32            // K-panel depth (bf16); 4 x 16B chunks per row
#define WELEM (HD*ID*NE) // elems per weight tensor = 8388608
#define CPAD 16          // counts padded: one 64B line per expert counter

// pack two fp32 -> two bf16 (truncate): one v_perm_b32
__device__ __forceinline__ unsigned pk2(float a, float b) {
    return __builtin_amdgcn_perm(__float_as_uint(b), __float_as_uint(a),
                                 0x07060302u);
}
__device__ __forceinline__ bf16x8 cvt8(const float* __restrict__ p) {
    float4 a = *(const float4*)p;
    float4 b = *(const float4*)(p + 4);
    union { bf16x8 v; unsigned u[4]; } r;
    r.u[0] = pk2(a.x, a.y); r.u[1] = pk2(a.z, a.w);
    r.u[2] = pk2(b.x, b.y); r.u[3] = pk2(b.z, b.w);
    return r.v;
}
__device__ __forceinline__ short f2bf(float f) {  // RTNE
    unsigned u = __float_as_uint(f);
    return (short)((u + 0x7fffu + ((u >> 16) & 1u)) >> 16);
}
__device__ __forceinline__ float bf2f(short s) {
    return __uint_as_float(((unsigned)(unsigned short)s) << 16);
}
// async 16B-per-lane global->LDS DMA; lds dest = wave-uniform base + lane*16
__device__ __forceinline__ void load_lds16(const short* g, short* l) {
    __builtin_amdgcn_global_load_lds(
        (const __attribute__((address_space(1))) unsigned*)g,
        (__attribute__((address_space(3))) unsigned*)l, 16, 0, 0);
}

#define MFMA_BF16 __builtin_amdgcn_mfma_f32_16x16x32_bf16

// ---------------- kernel 1: fused prep (router ++ weight conversion) ------
// Blocks 0..511: router (4 tokens each) — placed FIRST so they are
// dispatched early and finish while conv blocks stream weights; gemm1
// depends on router output via stream ordering anyway, and router's
// compute overlaps under conv's HBM-bound phase instead of serializing.
// Blocks 512..12799: fp32->bf16 weight conversion (3 tensors x 4096 blks).
// counts[] zeroing is a stream-ordered hipMemsetAsync BEFORE this kernel
// (block dispatch order is undefined -> cannot zero in-kernel, G16).
__global__ __launch_bounds__(256) void prep_k(
        const float* __restrict__ x, const float* __restrict__ gw,
        const float* __restrict__ eb,
        int* __restrict__ tk_idx, float* __restrict__ tk_w,
        short* __restrict__ xb,
        int* __restrict__ counts, int* __restrict__ tok_list,
        int* __restrict__ pair_slot,
        const float* __restrict__ s0, short* __restrict__ d0,
        const float* __restrict__ s1, short* __restrict__ d1,
        const float* __restrict__ s2, short* __restrict__ d2) {
    int bid = blockIdx.x;
    if (bid >= 512) {                       // ---- conv path ----
        int cid = bid - 512;                // 0..12287
        int t   = cid >> 12;                // tensor 0..2 (4096 blocks each)
        int blk = cid & 4095;
        const float* src = (t == 0) ? s0 : (t == 1) ? s1 : s2;
        short* dst       = (t == 0) ? d0 : (t == 1) ? d1 : d2;
        size_t i = ((size_t)blk * 256 + threadIdx.x) * 8;
        union { bf16x8 v; uint4 q; } r;
        r.v = cvt8(src + i);
        *(uint4*)(dst + i) = r.q;
        return;
    }
    // ---- router path (r6-proven body) ----
    int wid  = (bid * 256 + threadIdx.x) >> 6;   // token id
    int lane = threadIdx.x & 63;

    const float* xr = x + (size_t)wid * HD + lane * 16;
    float xv[16];
#pragma unroll
    for (int c = 0; c < 4; c++) {
        float4 v = *(const float4*)(xr + c * 4);
        xv[4 * c] = v.x; xv[4 * c + 1] = v.y; xv[4 * c + 2] = v.z; xv[4 * c + 3] = v.w;
    }
    {   // bf16 copy of x, coalesced
        union { uint4 q; unsigned u[4]; } w0, w1;
        w0.u[0] = pk2(xv[0], xv[1]);  w0.u[1] = pk2(xv[2], xv[3]);
        w0.u[2] = pk2(xv[4], xv[5]);  w0.u[3] = pk2(xv[6], xv[7]);
        w1.u[0] = pk2(xv[8], xv[9]);  w1.u[1] = pk2(xv[10], xv[11]);
        w1.u[2] = pk2(xv[12], xv[13]); w1.u[3] = pk2(xv[14], xv[15]);
        short* d = xb + ((size_t)wid << 10) + lane * 16;
        *(uint4*)d = w0.q;
        *(uint4*)(d + 8) = w1.q;
    }

    float logits[NE];
#pragma unroll
    for (int e = 0; e < NE; e++) {
        const float* gr = gw + e * HD + lane * 16;
        float p = 0.f;
#pragma unroll
        for (int c = 0; c < 4; c++) {
            float4 v = *(const float4*)(gr + c * 4);
            p += xv[4 * c] * v.x + xv[4 * c + 1] * v.y +
                 xv[4 * c + 2] * v.z + xv[4 * c + 3] * v.w;
        }
#pragma unroll
        for (int s = 32; s > 0; s >>= 1) p += __shfl_xor(p, s, 64);
        logits[e] = p;
    }

    float scores[NE], sc[NE];
#pragma unroll
    for (int e = 0; e < NE; e++) {
        scores[e] = 1.f / (1.f + __expf(-logits[e]));
        sc[e] = scores[e] + eb[e];
    }

    float gs[4];
#pragma unroll
    for (int g = 0; g < 4; g++) {
        float a = sc[4 * g], b = sc[4 * g + 1], c = sc[4 * g + 2], d = sc[4 * g + 3];
        float h1 = fmaxf(a, b), l1 = fminf(a, b);
        float h2 = fmaxf(c, d), l2 = fminf(c, d);
        gs[g] = fmaxf(h1, h2) + fmaxf(fminf(h1, h2), fmaxf(l1, l2));
    }
    int g0 = 0; float b0 = gs[0];
#pragma unroll
    for (int g = 1; g < 4; g++) if (gs[g] > b0) { b0 = gs[g]; g0 = g; }
    int g1 = -1; float b1 = -1e30f;
#pragma unroll
    for (int g = 0; g < 4; g++) if (g != g0 && gs[g] > b1) { b1 = gs[g]; g1 = g; }

    int taken = 0;
    int bid_[TOPK]; float bsc[TOPK]; float wsum = 0.f;
#pragma unroll
    for (int k = 0; k < TOPK; k++) {
        float bv = -1e30f; int bi = 0; float bs = 0.f;
#pragma unroll
        for (int e = 0; e < NE; e++) {
            int grp = e >> 2;
            bool ok = ((grp == g0) || (grp == g1)) && !((taken >> e) & 1);
            if (ok && sc[e] > bv) { bv = sc[e]; bi = e; bs = scores[e]; }
        }
        taken |= (1 << bi);
        bid_[k] = bi; bsc[k] = bs; wsum += bs;
    }
    // fused assignment: 4 parallel lanes, line-padded counters (r6-proven)
    if (lane < TOPK) {
        float inv = 1.0f / (wsum + 1e-20f);
        int ee = bid_[lane];
        int slot = atomicAdd(&counts[ee * CPAD], 1);
        tok_list[ee * T_TOK + slot] = wid;
        pair_slot[wid * TOPK + lane] = slot;
        tk_idx[wid * TOPK + lane] = ee;
        tk_w[wid * TOPK + lane]   = bsc[lane] * inv;
    }
}

// ---------------- kernel 2: GEMM1 (x @ [gate|up]^T, silu*up -> act) -------
// grid (experts=16, n_slices=8, m_tiles=16): linear%8 = e%8 (expert-affine
// XCD mapping, r5-proven). Block tile M=128 x N=64 (gate AND up), BK=32,
// 4 waves (2x2), wave 64x32. DEPTH-2 pipeline: 3 LDS buffers (48.5 KB ->
// 3 blocks/CU — r8 proved TLP dominates depth), counted vmcnt(8) steady
// (2 panels x 4 loads in flight), tail 4 -> 0. Chunk swizzle: source
// chunk c^((r>>1)&3), read slot qd^((r>>1)&3).
__global__ __launch_bounds__(256) void gemm1_k(
        const short* __restrict__ xb,
        const short* __restrict__ gpb,
        const short* __restrict__ upb,
        const int* __restrict__ counts,
        const int* __restrict__ tok_list,
        short* __restrict__ act) {
    __shared__ short xs[3][128 * BK];   // 8 KB per buf
    __shared__ short gs[3][64 * BK];    // 4 KB per buf
    __shared__ short us[3][64 * BK];    // 4 KB per buf
    __shared__ int   tok_s[128];

    int e = blockIdx.x;
    int cnt = counts[e * CPAD];
    int base = blockIdx.z * 128;
    if (base >= cnt) return;
    int off = 0;
#pragma unroll
    for (int q = 0; q < NE; q++) if (q < e) off += counts[q * CPAD];
    int arow0 = off + base;

    int tid = threadIdx.x;
    if (tid < 128) {
        int s = base + tid;
        tok_s[tid] = (s < cnt) ? tok_list[e * T_TOK + s] : tok_list[e * T_TOK];
    }
    __syncthreads();

    int wv = tid >> 6, lane = tid & 63;
    int qd = lane >> 4, l16 = lane & 15;
    int wm = (wv >> 1) * 64, wn = (wv & 1) * 32;
    int nb0 = blockIdx.y * 64;
    const short* gp = gpb + (size_t)e * ID * HD + (size_t)nb0 * HD;
    const short* up = upb + (size_t)e * ID * HD + (size_t)nb0 * HD;

    // staging: 16B chunks, 4 per row. x: 512 chunks -> 2/thread; g,u: 1 each.
    const short* xsg[2]; short* xld[2];
#pragma unroll
    for (int i = 0; i < 2; i++) {
        int idx = i * 256 + tid, r = idx >> 2, c = idx & 3;
        int f = (r >> 1) & 3;
        xsg[i] = xb + ((size_t)tok_s[r] << 10) + ((c ^ f) << 3);
        xld[i] = &xs[0][(i * 256 + wv * 64) * 8];
    }
    const short* gsg; const short* usg; short* gld; short* uld;
    {
        int r = tid >> 2, c = tid & 3;
        int f = (r >> 1) & 3;
        size_t so = (size_t)r * HD + ((c ^ f) << 3);
        gsg = gp + so;
        usg = up + so;
        gld = &gs[0][(wv * 64) * 8];
        uld = &us[0][(wv * 64) * 8];
    }

    f32x4 accg[4][2] = {};
    f32x4 accu[4][2] = {};

    // 4 global_load_lds per thread per panel
    auto STAGE = [&](int kp, int b) {
        load_lds16(xsg[0] + kp, xld[0] + b * (128 * BK));
        load_lds16(xsg[1] + kp, xld[1] + b * (128 * BK));
        load_lds16(gsg + kp, gld + b * (64 * BK));
        load_lds16(usg + kp, uld + b * (64 * BK));
    };
    auto COMPUTE = [&](int b) {
        const short* xsb = xs[b];
        const short* gsb = gs[b];
        const short* usb = us[b];
        bf16x8 af[4], bg[2], bu[2];
#pragma unroll
        for (int i = 0; i < 4; i++) {
            int r = wm + i * 16 + l16;
            af[i] = *(const bf16x8*)&xsb[r * BK + ((qd ^ ((r >> 1) & 3)) << 3)];
        }
#pragma unroll
        for (int j = 0; j < 2; j++) {
            int r = wn + j * 16 + l16;
            int lo = r * BK + ((qd ^ ((r >> 1) & 3)) << 3);
            bg[j] = *(const bf16x8*)&gsb[lo];
            bu[j] = *(const bf16x8*)&usb[lo];
        }
#pragma unroll
        for (int i = 0; i < 4; i++)
#pragma unroll
            for (int j = 0; j < 2; j++) {
                accg[i][j] = MFMA_BF16(af[i], bg[j], accg[i][j], 0, 0, 0);
                accu[i][j] = MFMA_BF16(af[i], bu[j], accu[i][j], 0, 0, 0);
            }
    };

    constexpr int NP = HD / BK;   // 32 panels
    STAGE(0, 0); STAGE(BK, 1);
    int b = 0;
#pragma unroll 1
    for (int p = 0; p < NP; ++p) {
        int bn = b + 2; if (bn >= 3) bn -= 3;
        if (p + 2 < NP) {
            STAGE((p + 2) * BK, bn);
            asm volatile("s_waitcnt vmcnt(8)" ::: "memory");  // panel p landed
        } else if (p + 1 < NP) {
            asm volatile("s_waitcnt vmcnt(4)" ::: "memory");
        } else {
            asm volatile("s_waitcnt vmcnt(0)" ::: "memory");
        }
        __builtin_amdgcn_s_barrier();
        asm volatile("" ::: "memory");   // no ds_read hoists above barrier
        COMPUTE(b);
        asm volatile("" ::: "memory");   // no ds_read sinks below barrier
        __builtin_amdgcn_s_barrier();    // buf b free for DMA overwrite
        b = (b == 2) ? 0 : b + 1;
    }

    // epilogue: silu(g)*u -> bf16 act rows
#pragma unroll
    for (int i = 0; i < 4; i++)
#pragma unroll
        for (int j = 0; j < 2; j++)
#pragma unroll
            for (int r = 0; r < 4; r++) {
                int m = wm + i * 16 + qd * 4 + r;
                if (base + m < cnt) {
                    float g = accg[i][j][r], u = accu[i][j][r];
                    float a = g / (1.f + __expf(-g)) * u;
                    act[(size_t)(arow0 + m) * ID + nb0 + wn + j * 16 + l16] = f2bf(a);
                }
            }
}

// ---------------- kernel 3: GEMM2 (act @ down^T -> yexp bf16) -------------
// grid (experts=16, h_slices=8, m_tiles=16): expert-affine like gemm1.
// Block tile M=128 x N=128, BK=32, wave 64x64. DEPTH-2 pipeline: 3 LDS
// buffers (48 KB -> 3 blocks/CU), vmcnt(8) steady.
__global__ __launch_bounds__(256) void gemm2_k(
        const short* __restrict__ act,
        const short* __restrict__ dpb,
        const int* __restrict__ counts,
        short* __restrict__ yexp) {
    __shared__ short as_[3][128 * BK];  // 8 KB per buf
    __shared__ short ds_[3][128 * BK];  // 8 KB per buf

    int e = blockIdx.x;
    int cnt = counts[e * CPAD];
    int base = blockIdx.z * 128;
    if (base >= cnt) return;
    int off = 0;
#pragma unroll
    for (int q = 0; q < NE; q++) if (q < e) off += counts[q * CPAD];
    int arow0 = off + base;

    int tid = threadIdx.x;
    int wv = tid >> 6, lane = tid & 63;
    int qd = lane >> 4, l16 = lane & 15;
    int wm = (wv >> 1) * 64, wn = (wv & 1) * 64;
    int hb0 = blockIdx.y * 128;
    const short* dp = dpb + (size_t)e * HD * ID + (size_t)hb0 * ID;

    // staging: A 512 chunks -> 2/thread; B 512 chunks -> 2/thread.
    const short* asg[2]; const short* dsg[2]; short* ald[2]; short* dld[2];
#pragma unroll
    for (int i = 0; i < 2; i++) {
        int idx = i * 256 + tid, r = idx >> 2, c = idx & 3;
        int f = (r >> 1) & 3;
        int sw = (c ^ f) << 3;
        asg[i] = act + (size_t)(arow0 + r) * ID + sw;
        dsg[i] = dp + (size_t)r * ID + sw;
        ald[i] = &as_[0][(i * 256 + wv * 64) * 8];
        dld[i] = &ds_[0][(i * 256 + wv * 64) * 8];
    }

    f32x4 acc[4][4] = {};

    auto STAGE = [&](int kp, int b) {
        load_lds16(asg[0] + kp, ald[0] + b * (128 * BK));
        load_lds16(asg[1] + kp, ald[1] + b * (128 * BK));
        load_lds16(dsg[0] + kp, dld[0] + b * (128 * BK));
        load_lds16(dsg[1] + kp, dld[1] + b * (128 * BK));
    };
    auto COMPUTE = [&](int b) {
        const short* asb = as_[b];
        const short* dsb = ds_[b];
        bf16x8 af[4], bd[4];
#pragma unroll
        for (int i = 0; i < 4; i++) {
            int r = wm + i * 16 + l16;
            af[i] = *(const bf16x8*)&asb[r * BK + ((qd ^ ((r >> 1) & 3)) << 3)];
            int r2 = wn + i * 16 + l16;
            bd[i] = *(const bf16x8*)&dsb[r2 * BK + ((qd ^ ((r2 >> 1) & 3)) << 3)];
        }
#pragma unroll
        for (int i = 0; i < 4; i++)
#pragma unroll
            for (int j = 0; j < 4; j++)
                acc[i][j] = MFMA_BF16(af[i], bd[j], acc[i][j], 0, 0, 0);
    };

    constexpr int NP = ID / BK;   // 16 panels
    STAGE(0, 0); STAGE(BK, 1);
    int b = 0;
#pragma unroll 1
    for (int p = 0; p < NP; ++p) {
        int bn = b + 2; if (bn >= 3) bn -= 3;
        if (p + 2 < NP) {
            STAGE((p + 2) * BK, bn);
            asm volatile("s_waitcnt vmcnt(8)" ::: "memory");
        } else if (p + 1 < NP) {
            asm volatile("s_waitcnt vmcnt(4)" ::: "memory");
        } else {
            asm volatile("s_waitcnt vmcnt(0)" ::: "memory");
        }
        __builtin_amdgcn_s_barrier();
        asm volatile("" ::: "memory");
        COMPUTE(b);
        asm volatile("" ::: "memory");
        __builtin_amdgcn_s_barrier();
        b = (b == 2) ? 0 : b + 1;
    }

#pragma unroll
    for (int i = 0; i < 4; i++)
#pragma unroll
        for (int j = 0; j < 4; j++)
#pragma unroll
            for (int r = 0; r < 4; r++) {
                int m = wm + i * 16 + qd * 4 + r;
                if (base + m < cnt)
                    yexp[(size_t)(arow0 + m) * HD + hb0 + wn + j * 16 + l16] =
                        f2bf(acc[i][j][r]);
            }
}

// ---------------- kernel 4: weighted combine (atomic-free) ----------------
// 2 tokens per block; thread covers 8 cols. Computes expert offsets from
// padded counts locally. Fully overwrites out.
__global__ __launch_bounds__(256) void combine_k(
        const short* __restrict__ yexp,
        const int* __restrict__ counts,
        const int* __restrict__ tk_idx, const float* __restrict__ tk_w,
        const int* __restrict__ pair_slot,
        float* __restrict__ out) {
    __shared__ int offs_s[NE];
    if (threadIdx.x == 0) {
        int a = 0;
#pragma unroll
        for (int e = 0; e < NE; e++) { offs_s[e] = a; a += counts[e * CPAD]; }
    }
    __syncthreads();

    int t = blockIdx.x * 2 + (threadIdx.x >> 7);
    int i = threadIdx.x & 127;          // col group of 8
    float acc[8] = {};
#pragma unroll
    for (int k = 0; k < TOPK; k++) {
        int p = t * TOPK + k;
        int e = tk_idx[p];
        int row = offs_s[e] + pair_slot[p];
        float w = tk_w[p];
        bf16x8 v = *(const bf16x8*)(yexp + (size_t)row * HD + i * 8);
#pragma unroll
        for (int j = 0; j < 8; j++) acc[j] += w * bf2f(v[j]);
    }
    float4 o0 = {acc[0], acc[1], acc[2], acc[3]};
    float4 o1 = {acc[4], acc[5], acc[6], acc[7]};
    float* d = out + (size_t)t * HD + i * 8;
    *(float4*)d = o0;
    *(float4*)(d + 4) = o1;
}

// ---------------- launch ----------------
extern "C" void kernel_launch(void* const* d_in, const int* in_sizes, int n_in,
                              void* d_out, int out_size, void* d_ws, size_t ws_size,
                              hipStream_t stream) {
    const float* x  = (const float*)d_in[0];   // hidden_states [T,H]
    const float* gw = (const float*)d_in[1];   // gate_weight  [E,H]
    const float* eb = (const float*)d_in[2];   // e_bias       [E]
    const float* gp = (const float*)d_in[3];   // gate_proj [E,I,H]
    const float* up = (const float*)d_in[4];   // up_proj   [E,I,H]
    const float* dp = (const float*)d_in[5];   // down_proj [E,H,I]

    short* gpb = (short*)d_ws;                  // bf16 weights: 3 x 16.8 MB
    short* upb = gpb + WELEM;
    short* dpb = upb + WELEM;
    short* xb  = dpb + WELEM;                   // x bf16: 2048x1024
    short* act = xb + (size_t)T_TOK * HD;       // (8192+128) x 512 bf16
    int* counts    = (int*)(act + (size_t)(T_TOK * TOPK + 128) * ID); // NE*CPAD
    int* tok_list  = counts + NE * CPAD;              // E*T
    int* pair_slot = tok_list + NE * T_TOK;           // T*4
    int* tk_idx    = pair_slot + T_TOK * TOPK;        // T*4
    float* tk_w    = (float*)(tk_idx + T_TOK * TOPK); // T*4
    // yexp bf16 (8192 x 1024 = 16.8 MB) aliases gpb (dead after gemm1;
    // exact size match). Same-stream ordering makes this safe.
    short* yexp = gpb;

    hipMemsetAsync(counts, 0, NE * CPAD * sizeof(int), stream);

    prep_k<<<512 + 3 * (WELEM / 8 / 256), 256, 0, stream>>>(
        x, gw, eb, tk_idx, tk_w, xb, counts, tok_list, pair_slot,
        gp, gpb, up, upb, dp, dpb);
    gemm1_k<<<dim3(NE, ID / 64, T_TOK / 128), 256, 0, stream>>>(
        xb, gpb, upb, counts, tok_list, act);
    gemm2_k<<<dim3(NE, HD / 128, T_TOK / 128), 256, 0, stream>>>(
        act, dpb, counts, yexp);
    combine_k<<<T_TOK / 2, 256, 0, stream>>>(yexp, counts, tk_idx, tk_w,
                                             pair_slot, (float*)d_out);
}